// Round 1
// baseline (812.085 us; speedup 1.0000x reference)
//
#include <hip/hip_runtime.h>

#define DD 128

// ---------------- CSR build ----------------

__global__ __launch_bounds__(256) void hist_kernel(const int* __restrict__ src,
                                                   const int* __restrict__ dst,
                                                   int* __restrict__ cnt_out,
                                                   int* __restrict__ cnt_in, int e) {
  int i = blockIdx.x * blockDim.x + threadIdx.x;
  if (i < e) {
    atomicAdd(&cnt_out[src[i]], 1);
    atomicAdd(&cnt_in[dst[i]], 1);
  }
}

// Single-block exclusive scan of cnt[0..n) -> row_ptr[0..n], cursor copy.
__global__ __launch_bounds__(1024) void scan_kernel(const int* __restrict__ cnt,
                                                    int* __restrict__ row_ptr,
                                                    int* __restrict__ cursor, int n) {
  __shared__ int wsum[16];
  __shared__ int chunk_total;
  int tid = threadIdx.x;
  int lane = tid & 63;
  int wid = tid >> 6;
  int running = 0;
  const int CHUNK = 1024 * 8;
  for (int base = 0; base < n; base += CHUNK) {
    int idx0 = base + tid * 8;
    int v[8];
#pragma unroll
    for (int i = 0; i < 8; ++i) {
      int id = idx0 + i;
      v[i] = (id < n) ? cnt[id] : 0;
    }
#pragma unroll
    for (int i = 1; i < 8; ++i) v[i] += v[i - 1];
    int tsum = v[7];
    // wave-inclusive scan of per-thread sums
    int sc = tsum;
#pragma unroll
    for (int d = 1; d < 64; d <<= 1) {
      int t = __shfl_up(sc, d, 64);
      if (lane >= d) sc += t;
    }
    if (lane == 63) wsum[wid] = sc;
    __syncthreads();
    if (wid == 0) {
      int wv = (lane < 16) ? wsum[lane] : 0;
      int s2 = wv;
#pragma unroll
      for (int d = 1; d < 16; d <<= 1) {
        int t = __shfl_up(s2, d, 64);
        if (lane >= d) s2 += t;
      }
      if (lane < 16) wsum[lane] = s2 - wv;  // exclusive wave offsets
      if (lane == 15) chunk_total = s2;     // inclusive total of this chunk
    }
    __syncthreads();
    int off = running + wsum[wid] + (sc - tsum);
#pragma unroll
    for (int i = 0; i < 8; ++i) {
      int id = idx0 + i;
      if (id < n) {
        int ex = off + (i ? v[i - 1] : 0);
        row_ptr[id] = ex;
        cursor[id] = ex;
      }
    }
    running += chunk_total;
    __syncthreads();  // protect wsum/chunk_total reuse next chunk
  }
  if (tid == 0) row_ptr[n] = running;
}

__global__ __launch_bounds__(256) void norm_kernel(const int* __restrict__ cnt_out,
                                                   const int* __restrict__ cnt_in,
                                                   float* __restrict__ norm_src,
                                                   float* __restrict__ norm_dst, int n) {
  int i = blockIdx.x * blockDim.x + threadIdx.x;
  if (i < n) {
    int co = cnt_out[i]; if (co < 1) co = 1;
    int ci = cnt_in[i]; if (ci < 1) ci = 1;
    norm_src[i] = 1.0f / sqrtf((float)co);
    norm_dst[i] = 1.0f / sqrtf((float)ci);
  }
}

__global__ __launch_bounds__(256) void fill_kernel(const int* __restrict__ src,
                                                   const int* __restrict__ dst,
                                                   int* __restrict__ cursor,
                                                   int* __restrict__ adj, int e) {
  int i = blockIdx.x * blockDim.x + threadIdx.x;
  if (i < e) {
    int p = atomicAdd(&cursor[dst[i]], 1);
    adj[p] = src[i];
  }
}

// ---------------- per-layer kernels ----------------

// One wave per dst node: out[n] = norm_dst[n] * sum_{s in adj[n]} norm_src[s]*h[s]
__global__ __launch_bounds__(256) void agg_kernel(const float* __restrict__ h,
                                                  const int* __restrict__ adj,
                                                  const int* __restrict__ row_ptr,
                                                  const float* __restrict__ norm_src,
                                                  const float* __restrict__ norm_dst,
                                                  float* __restrict__ out, int n) {
  int node = blockIdx.x * 4 + (threadIdx.x >> 6);
  int lane = threadIdx.x & 63;
  if (node >= n) return;
  int beg = row_ptr[node];
  int end = row_ptr[node + 1];
  float2 acc = make_float2(0.f, 0.f);
  const float* hp = h + lane * 2;
  int j = beg;
  for (; j + 1 < end; j += 2) {  // unroll x2: two outstanding row loads
    int s0 = adj[j];
    int s1 = adj[j + 1];
    float w0 = norm_src[s0];
    float w1 = norm_src[s1];
    float2 v0 = *(const float2*)(hp + (size_t)s0 * DD);
    float2 v1 = *(const float2*)(hp + (size_t)s1 * DD);
    acc.x = fmaf(w0, v0.x, acc.x);
    acc.y = fmaf(w0, v0.y, acc.y);
    acc.x = fmaf(w1, v1.x, acc.x);
    acc.y = fmaf(w1, v1.y, acc.y);
  }
  if (j < end) {
    int s0 = adj[j];
    float w0 = norm_src[s0];
    float2 v0 = *(const float2*)(hp + (size_t)s0 * DD);
    acc.x = fmaf(w0, v0.x, acc.x);
    acc.y = fmaf(w0, v0.y, acc.y);
  }
  float nd = norm_dst[node];
  float2 o = make_float2(acc.x * nd, acc.y * nd);
  *(float2*)(out + (size_t)node * DD + lane * 2) = o;
}

// In-place: X[r,:] = relu(X[r,:] @ W + b). 32-row tile in LDS, 256 thr, 4x4 acc.
__global__ __launch_bounds__(256) void gemm_relu_kernel(float* __restrict__ X,
                                                        const float* __restrict__ W,
                                                        const float* __restrict__ bias,
                                                        int n) {
  __shared__ float Xs[32][DD];
  int tid = threadIdx.x;
  int row0 = blockIdx.x * 32;
  // load 32x128 tile (1024 float4; 4 per thread, coalesced)
#pragma unroll
  for (int i = 0; i < 4; ++i) {
    int f4 = tid + 256 * i;
    int r = f4 >> 5;
    int c4 = f4 & 31;
    float4 v = make_float4(0.f, 0.f, 0.f, 0.f);
    if (row0 + r < n) v = *(const float4*)(X + (size_t)(row0 + r) * DD + c4 * 4);
    *(float4*)&Xs[r][c4 * 4] = v;
  }
  __syncthreads();
  int tx = tid & 31;   // 32 col-groups of 4 -> cols tx*4..tx*4+3
  int ty = tid >> 5;   // 8 row-groups of 4 -> rows ty*4..ty*4+3
  float acc[4][4] = {};
#pragma unroll 4
  for (int k = 0; k < DD; ++k) {
    float4 w = *(const float4*)(W + (size_t)k * DD + tx * 4);
#pragma unroll
    for (int i = 0; i < 4; ++i) {
      float xv = Xs[ty * 4 + i][k];  // broadcast within half-wave
      acc[i][0] = fmaf(xv, w.x, acc[i][0]);
      acc[i][1] = fmaf(xv, w.y, acc[i][1]);
      acc[i][2] = fmaf(xv, w.z, acc[i][2]);
      acc[i][3] = fmaf(xv, w.w, acc[i][3]);
    }
  }
  float4 bv = *(const float4*)(bias + tx * 4);
#pragma unroll
  for (int i = 0; i < 4; ++i) {
    int r = row0 + ty * 4 + i;
    if (r < n) {
      float4 o;
      o.x = fmaxf(acc[i][0] + bv.x, 0.f);
      o.y = fmaxf(acc[i][1] + bv.y, 0.f);
      o.z = fmaxf(acc[i][2] + bv.z, 0.f);
      o.w = fmaxf(acc[i][3] + bv.w, 0.f);
      *(float4*)(X + (size_t)r * DD + tx * 4) = o;
    }
  }
}

// ---------------- launch ----------------

extern "C" void kernel_launch(void* const* d_in, const int* in_sizes, int n_in,
                              void* d_out, int out_size, void* d_ws, size_t ws_size,
                              hipStream_t stream) {
  const float* feat = (const float*)d_in[0];
  const int* src = (const int*)d_in[1];
  const int* dst = (const int*)d_in[2];
  const float* W = (const float*)d_in[3];
  const float* b = (const float*)d_in[4];
  const int N = in_sizes[0] / DD;
  const int E = in_sizes[1];
  const int L = in_sizes[3] / (DD * DD);

  char* p = (char*)d_ws;
  auto alloc = [&](size_t bytes) {
    void* r = (void*)p;
    p += (bytes + 255) & ~(size_t)255;
    return r;
  };
  int* cnt_in = (int*)alloc((size_t)N * 4);
  int* cnt_out = (int*)alloc((size_t)N * 4);
  int* row_ptr = (int*)alloc(((size_t)N + 1) * 4);
  int* cursor = (int*)alloc((size_t)N * 4);
  int* adj = (int*)alloc((size_t)E * 4);
  float* norm_src = (float*)alloc((size_t)N * 4);
  float* norm_dst = (float*)alloc((size_t)N * 4);
  float* hbuf = (float*)alloc((size_t)N * DD * 4);

  hipMemsetAsync(cnt_in, 0, (size_t)N * 4, stream);
  hipMemsetAsync(cnt_out, 0, (size_t)N * 4, stream);
  hist_kernel<<<(E + 255) / 256, 256, 0, stream>>>(src, dst, cnt_out, cnt_in, E);
  scan_kernel<<<1, 1024, 0, stream>>>(cnt_in, row_ptr, cursor, N);
  norm_kernel<<<(N + 255) / 256, 256, 0, stream>>>(cnt_out, cnt_in, norm_src, norm_dst, N);
  fill_kernel<<<(E + 255) / 256, 256, 0, stream>>>(src, dst, cursor, adj, E);

  float* out_f = (float*)d_out;
  for (int l = 0; l < L; ++l) {
    float* ho = (((L - 1 - l) % 2) == 0) ? out_f : hbuf;
    const float* hi = (l == 0) ? feat
                               : ((((L - l) % 2) == 0) ? (const float*)out_f
                                                       : (const float*)hbuf);
    agg_kernel<<<(N + 3) / 4, 256, 0, stream>>>(hi, adj, row_ptr, norm_src, norm_dst,
                                                ho, N);
    gemm_relu_kernel<<<(N + 31) / 32, 256, 0, stream>>>(
        ho, W + (size_t)l * DD * DD, b + (size_t)l * DD, N);
  }
}

// Round 2
// 698.580 us; speedup vs baseline: 1.1625x; 1.1625x over previous
//
#include <hip/hip_runtime.h>

#define DD 128

// ---------------- CSR build ----------------

__global__ __launch_bounds__(256) void hist_kernel(const int* __restrict__ src,
                                                   const int* __restrict__ dst,
                                                   int* __restrict__ cnt_out,
                                                   int* __restrict__ cnt_in, int e) {
  int i = blockIdx.x * blockDim.x + threadIdx.x;
  if (i < e) {
    atomicAdd(&cnt_out[src[i]], 1);
    atomicAdd(&cnt_in[dst[i]], 1);
  }
}

// Single-block exclusive scan of cnt[0..n) -> row_ptr[0..n], cursor copy.
__global__ __launch_bounds__(1024) void scan_kernel(const int* __restrict__ cnt,
                                                    int* __restrict__ row_ptr,
                                                    int* __restrict__ cursor, int n) {
  __shared__ int wsum[16];
  __shared__ int chunk_total;
  int tid = threadIdx.x;
  int lane = tid & 63;
  int wid = tid >> 6;
  int running = 0;
  const int CHUNK = 1024 * 8;
  for (int base = 0; base < n; base += CHUNK) {
    int idx0 = base + tid * 8;
    int v[8];
#pragma unroll
    for (int i = 0; i < 8; ++i) {
      int id = idx0 + i;
      v[i] = (id < n) ? cnt[id] : 0;
    }
#pragma unroll
    for (int i = 1; i < 8; ++i) v[i] += v[i - 1];
    int tsum = v[7];
    int sc = tsum;
#pragma unroll
    for (int d = 1; d < 64; d <<= 1) {
      int t = __shfl_up(sc, d, 64);
      if (lane >= d) sc += t;
    }
    if (lane == 63) wsum[wid] = sc;
    __syncthreads();
    if (wid == 0) {
      int wv = (lane < 16) ? wsum[lane] : 0;
      int s2 = wv;
#pragma unroll
      for (int d = 1; d < 16; d <<= 1) {
        int t = __shfl_up(s2, d, 64);
        if (lane >= d) s2 += t;
      }
      if (lane < 16) wsum[lane] = s2 - wv;  // exclusive wave offsets
      if (lane == 15) chunk_total = s2;     // inclusive total of this chunk
    }
    __syncthreads();
    int off = running + wsum[wid] + (sc - tsum);
#pragma unroll
    for (int i = 0; i < 8; ++i) {
      int id = idx0 + i;
      if (id < n) {
        int ex = off + (i ? v[i - 1] : 0);
        row_ptr[id] = ex;
        cursor[id] = ex;
      }
    }
    running += chunk_total;
    __syncthreads();
  }
  if (tid == 0) row_ptr[n] = running;
}

__global__ __launch_bounds__(256) void norm_kernel(const int* __restrict__ cnt_out,
                                                   const int* __restrict__ cnt_in,
                                                   float* __restrict__ norm_src,
                                                   float* __restrict__ norm_dst, int n) {
  int i = blockIdx.x * blockDim.x + threadIdx.x;
  if (i < n) {
    int co = cnt_out[i]; if (co < 1) co = 1;
    int ci = cnt_in[i]; if (ci < 1) ci = 1;
    norm_src[i] = 1.0f / sqrtf((float)co);
    norm_dst[i] = 1.0f / sqrtf((float)ci);
  }
}

__global__ __launch_bounds__(256) void fill_kernel(const int* __restrict__ src,
                                                   const int* __restrict__ dst,
                                                   int* __restrict__ cursor,
                                                   int* __restrict__ adj, int e) {
  int i = blockIdx.x * blockDim.x + threadIdx.x;
  if (i < e) {
    int p = atomicAdd(&cursor[dst[i]], 1);
    adj[p] = src[i];
  }
}

// ---------------- per-layer kernels ----------------

// One wave per dst node: out[n] = norm_dst[n] * sum_{s in adj[n]} norm_src[s]*h[s]
// Unroll x4: 4 row-loads in flight per wave (latency hiding).
__global__ __launch_bounds__(256) void agg_kernel(const float* __restrict__ h,
                                                  const int* __restrict__ adj,
                                                  const int* __restrict__ row_ptr,
                                                  const float* __restrict__ norm_src,
                                                  const float* __restrict__ norm_dst,
                                                  float* __restrict__ out, int n) {
  int node = blockIdx.x * 4 + (threadIdx.x >> 6);
  int lane = threadIdx.x & 63;
  if (node >= n) return;
  int beg = row_ptr[node];
  int end = row_ptr[node + 1];
  float accx = 0.f, accy = 0.f;
  const float* hp = h + lane * 2;
  int cnt = end - beg;
  int e4 = beg + (cnt & ~3);
  int j = beg;
  for (; j < e4; j += 4) {
    int s0 = adj[j];
    int s1 = adj[j + 1];
    int s2 = adj[j + 2];
    int s3 = adj[j + 3];
    float w0 = norm_src[s0];
    float w1 = norm_src[s1];
    float w2 = norm_src[s2];
    float w3 = norm_src[s3];
    float2 v0 = *(const float2*)(hp + (size_t)s0 * DD);
    float2 v1 = *(const float2*)(hp + (size_t)s1 * DD);
    float2 v2 = *(const float2*)(hp + (size_t)s2 * DD);
    float2 v3 = *(const float2*)(hp + (size_t)s3 * DD);
    accx = fmaf(w0, v0.x, accx);
    accy = fmaf(w0, v0.y, accy);
    accx = fmaf(w1, v1.x, accx);
    accy = fmaf(w1, v1.y, accy);
    accx = fmaf(w2, v2.x, accx);
    accy = fmaf(w2, v2.y, accy);
    accx = fmaf(w3, v3.x, accx);
    accy = fmaf(w3, v3.y, accy);
  }
  for (; j < end; ++j) {
    int s0 = adj[j];
    float w0 = norm_src[s0];
    float2 v0 = *(const float2*)(hp + (size_t)s0 * DD);
    accx = fmaf(w0, v0.x, accx);
    accy = fmaf(w0, v0.y, accy);
  }
  float nd = norm_dst[node];
  float2 o = make_float2(accx * nd, accy * nd);
  *(float2*)(out + (size_t)node * DD + lane * 2) = o;
}

// In-place: X[r,:] = relu(X[r,:] @ W + b).
// 64-row tile in LDS (32 KB), 256 thr, thread = 8 rows x 4 cols,
// k-vectorized ds_read_b128 on X, float4 W from global (L1/L2-resident).
__global__ __launch_bounds__(256) void gemm_relu_kernel(float* __restrict__ X,
                                                        const float* __restrict__ W,
                                                        const float* __restrict__ bias,
                                                        int n) {
  __shared__ float Xs[64][DD];
  int tid = threadIdx.x;
  int row0 = blockIdx.x * 64;
  // load 64x128 tile: 2048 float4, 8 per thread, coalesced
#pragma unroll
  for (int i = 0; i < 8; ++i) {
    int f4 = tid + 256 * i;
    int r = f4 >> 5;
    int c4 = f4 & 31;
    float4 v = make_float4(0.f, 0.f, 0.f, 0.f);
    if (row0 + r < n) v = *(const float4*)(X + (size_t)(row0 + r) * DD + c4 * 4);
    *(float4*)&Xs[r][c4 * 4] = v;
  }
  __syncthreads();
  int tx = tid & 31;   // col group: cols tx*4..tx*4+3
  int ty = tid >> 5;   // row group: rows ty*8..ty*8+7
  float acc[8][4] = {};
  const float4* wp0 = (const float4*)W + tx;
  for (int k4 = 0; k4 < DD / 4; ++k4) {
    const float4* wp = wp0 + (size_t)k4 * 4 * 32;
    float4 w0 = wp[0];
    float4 w1 = wp[32];
    float4 w2 = wp[64];
    float4 w3 = wp[96];
#pragma unroll
    for (int i = 0; i < 8; ++i) {
      float4 x = *(const float4*)&Xs[ty * 8 + i][k4 * 4];
      acc[i][0] = fmaf(x.x, w0.x, acc[i][0]);
      acc[i][1] = fmaf(x.x, w0.y, acc[i][1]);
      acc[i][2] = fmaf(x.x, w0.z, acc[i][2]);
      acc[i][3] = fmaf(x.x, w0.w, acc[i][3]);
      acc[i][0] = fmaf(x.y, w1.x, acc[i][0]);
      acc[i][1] = fmaf(x.y, w1.y, acc[i][1]);
      acc[i][2] = fmaf(x.y, w1.z, acc[i][2]);
      acc[i][3] = fmaf(x.y, w1.w, acc[i][3]);
      acc[i][0] = fmaf(x.z, w2.x, acc[i][0]);
      acc[i][1] = fmaf(x.z, w2.y, acc[i][1]);
      acc[i][2] = fmaf(x.z, w2.z, acc[i][2]);
      acc[i][3] = fmaf(x.z, w2.w, acc[i][3]);
      acc[i][0] = fmaf(x.w, w3.x, acc[i][0]);
      acc[i][1] = fmaf(x.w, w3.y, acc[i][1]);
      acc[i][2] = fmaf(x.w, w3.z, acc[i][2]);
      acc[i][3] = fmaf(x.w, w3.w, acc[i][3]);
    }
  }
  float4 bv = *(const float4*)(bias + tx * 4);
#pragma unroll
  for (int i = 0; i < 8; ++i) {
    int r = row0 + ty * 8 + i;
    if (r < n) {
      float4 o;
      o.x = fmaxf(acc[i][0] + bv.x, 0.f);
      o.y = fmaxf(acc[i][1] + bv.y, 0.f);
      o.z = fmaxf(acc[i][2] + bv.z, 0.f);
      o.w = fmaxf(acc[i][3] + bv.w, 0.f);
      *(float4*)(X + (size_t)r * DD + tx * 4) = o;
    }
  }
}

// ---------------- launch ----------------

extern "C" void kernel_launch(void* const* d_in, const int* in_sizes, int n_in,
                              void* d_out, int out_size, void* d_ws, size_t ws_size,
                              hipStream_t stream) {
  const float* feat = (const float*)d_in[0];
  const int* src = (const int*)d_in[1];
  const int* dst = (const int*)d_in[2];
  const float* W = (const float*)d_in[3];
  const float* b = (const float*)d_in[4];
  const int N = in_sizes[0] / DD;
  const int E = in_sizes[1];
  const int L = in_sizes[3] / (DD * DD);

  char* p = (char*)d_ws;
  auto alloc = [&](size_t bytes) {
    void* r = (void*)p;
    p += (bytes + 255) & ~(size_t)255;
    return r;
  };
  int* cnt_in = (int*)alloc((size_t)N * 4);
  int* cnt_out = (int*)alloc((size_t)N * 4);
  int* row_ptr = (int*)alloc(((size_t)N + 1) * 4);
  int* cursor = (int*)alloc((size_t)N * 4);
  int* adj = (int*)alloc((size_t)E * 4);
  float* norm_src = (float*)alloc((size_t)N * 4);
  float* norm_dst = (float*)alloc((size_t)N * 4);
  float* hbuf = (float*)alloc((size_t)N * DD * 4);

  hipMemsetAsync(cnt_in, 0, (size_t)N * 4, stream);
  hipMemsetAsync(cnt_out, 0, (size_t)N * 4, stream);
  hist_kernel<<<(E + 255) / 256, 256, 0, stream>>>(src, dst, cnt_out, cnt_in, E);
  scan_kernel<<<1, 1024, 0, stream>>>(cnt_in, row_ptr, cursor, N);
  norm_kernel<<<(N + 255) / 256, 256, 0, stream>>>(cnt_out, cnt_in, norm_src, norm_dst, N);
  fill_kernel<<<(E + 255) / 256, 256, 0, stream>>>(src, dst, cursor, adj, E);

  float* out_f = (float*)d_out;
  for (int l = 0; l < L; ++l) {
    float* ho = (((L - 1 - l) % 2) == 0) ? out_f : hbuf;
    const float* hi = (l == 0) ? feat
                               : ((((L - l) % 2) == 0) ? (const float*)out_f
                                                       : (const float*)hbuf);
    agg_kernel<<<(N + 3) / 4, 256, 0, stream>>>(hi, adj, row_ptr, norm_src, norm_dst,
                                                ho, N);
    gemm_relu_kernel<<<(N + 63) / 64, 256, 0, stream>>>(
        ho, W + (size_t)l * DD * DD, b + (size_t)l * DD, N);
  }
}